// Round 22
// baseline (388.340 us; speedup 1.0000x reference)
//
#include <hip/hip_runtime.h>
#include <hip/hip_bf16.h>
#include <math.h>

typedef __attribute__((ext_vector_type(8))) short bf16x8;
typedef __attribute__((ext_vector_type(8))) unsigned short u16x8;
typedef __attribute__((ext_vector_type(4))) float f32x4;
typedef __attribute__((ext_vector_type(4))) unsigned short u16x4;

__device__ inline unsigned short f2bf(float f) {
    union { float f; unsigned u; } v; v.f = f;
    unsigned r = (v.u + 0x7fff + ((v.u >> 16) & 1)) >> 16;   // RNE
    return (unsigned short)r;
}
__device__ inline float bf2f(unsigned short u) {
    union { unsigned u; float f; } v; v.u = ((unsigned)u) << 16; return v.f;
}

#define GLL16(gp, lp) __builtin_amdgcn_global_load_lds(                      \
    (const __attribute__((address_space(1))) void*)(gp),                     \
    (__attribute__((address_space(3))) void*)(lp), 16, 0, 0)

#define BAR() do { asm volatile("" ::: "memory");                            \
    __builtin_amdgcn_s_barrier();                                            \
    asm volatile("" ::: "memory"); } while (0)
#define VMW(n) asm volatile("s_waitcnt vmcnt(" #n ")" ::: "memory")

// ---------------------------------------------------------------------------
// 8-phase counted-vmcnt GEMM, BM=256 (r20/r21-verified: ~716 TF end-to-end;
// rocprof inflates this kernel). 256x256, BK=64, 8 waves, 128KB dbuf LDS.
// EPI=2: +bias+gelu.  EPI=3: fused drofe (Q scaled -> Cout, K -> Cout2).
// ---------------------------------------------------------------------------
template<int EPI>
__global__ __launch_bounds__(512, 2) void gemm8p(
    const unsigned short* __restrict__ A,
    const unsigned short* __restrict__ Bt,
    const float* __restrict__ bias,
    unsigned short* __restrict__ Cout,
    unsigned short* __restrict__ Cout2,
    const float* __restrict__ fbq,
    const float* __restrict__ demo,
    int M, int Nn, int K, int ldc)
{
    __shared__ unsigned char lds[131072];
    const int tid = threadIdx.x;
    const int w = tid >> 6, lane = tid & 63;
    const int lk = lane & 15, lg = lane >> 4;
    const int wr = w >> 2, wc = w & 3;
    const int nbn = Nn >> 8;
    const int nb = gridDim.x;
    int bid = blockIdx.x;
    int swz = (nb & 7) ? bid : (bid & 7) * (nb >> 3) + (bid >> 3);
    const int bm = (swz / nbn) << 8, bn = (swz % nbn) << 8;

    f32x4 acc[8][4] = {};
    bf16x8 af[4][2];
    bf16x8 bfr[2][2][2];

    auto stageH = [&](int buf, int op, int half, int kt) {
        #pragma unroll
        for (int i = 0; i < 2; ++i) {
            int s = tid + i * 512;
            int r = s >> 3, c = s & 7;
            int cs = c ^ (r & 7);
            const unsigned short* gp = (op == 0)
                ? A  + (size_t)(bm + half * 128 + r) * K + kt + cs * 8
                : Bt + (size_t)(bn + half * 128 + r) * K + kt + cs * 8;
            GLL16(gp, &lds[buf * 65536 + op * 32768 + half * 16384 + s * 16]);
        }
    };
    auto rdA = [&](int buf, int ah) {
        #pragma unroll
        for (int ml = 0; ml < 4; ++ml) {
            int row = (ah * 4 + ml) * 32 + wr * 16 + lk;
            #pragma unroll
            for (int kk = 0; kk < 2; ++kk) {
                int sl = (kk * 4 + lg) ^ (row & 7);
                af[ml][kk] = *(const bf16x8*)&lds[buf * 65536 + row * 128 + sl * 16];
            }
        }
    };
    auto rdB = [&](int buf, int g) {
        #pragma unroll
        for (int njl = 0; njl < 2; ++njl) {
            int row = (g * 2 + njl) * 64 + wc * 16 + lk;
            #pragma unroll
            for (int kk = 0; kk < 2; ++kk) {
                int sl = (kk * 4 + lg) ^ (row & 7);
                bfr[g][njl][kk] = *(const bf16x8*)&lds[buf * 65536 + 32768 + row * 128 + sl * 16];
            }
        }
    };
    auto mfmaq = [&](int ah, int g) {
        __builtin_amdgcn_s_setprio(1);
        #pragma unroll
        for (int ml = 0; ml < 4; ++ml)
            #pragma unroll
            for (int njl = 0; njl < 2; ++njl)
                #pragma unroll
                for (int kk = 0; kk < 2; ++kk)
                    acc[ah * 4 + ml][g * 2 + njl] =
                        __builtin_amdgcn_mfma_f32_16x16x32_bf16(
                            af[ml][kk], bfr[g][njl][kk],
                            acc[ah * 4 + ml][g * 2 + njl], 0, 0, 0);
        __builtin_amdgcn_s_setprio(0);
    };

    const int NT = K >> 6;
    stageH(0, 0, 0, 0);
    stageH(0, 1, 0, 0);
    stageH(0, 1, 1, 0);
    stageH(0, 0, 1, 0);
    stageH(1, 0, 0, 64);
    stageH(1, 1, 0, 64);
    stageH(1, 1, 1, 64);
    VMW(10); BAR();

    for (int t = 0; t < NT; ++t) {
        const int buf = t & 1;
        const int t1 = (t + 1 < NT) ? t + 1 : NT - 1;
        const int t2 = (t + 2 < NT) ? t + 2 : NT - 1;
        const int k1 = t1 << 6, k2 = t2 << 6;
        rdA(buf, 0); rdB(buf, 0);
        stageH(buf ^ 1, 0, 1, k1);
        mfmaq(0, 0);
        VMW(10); BAR();
        rdB(buf, 1);
        stageH(buf, 0, 0, k2);
        mfmaq(0, 1);
        VMW(10); BAR();
        rdA(buf, 1);
        stageH(buf, 1, 0, k2);
        mfmaq(1, 0);
        BAR();
        stageH(buf, 1, 1, k2);
        mfmaq(1, 1);
        VMW(10); BAR();
    }
    VMW(0);
    BAR();

    if (EPI == 3) {
        const float PI_F = 3.14159265358979323846f;
        const int b_ = bm >> 10;
        const float age = demo[b_ * 2 + 0], gen = demo[b_ * 2 + 1];
        #pragma unroll
        for (int mi = 0; mi < 8; ++mi) {
            #pragma unroll
            for (int nj = 0; nj < 4; ++nj) {
                int col = bn + nj * 64 + wc * 16 + lk;
                int i = (col & 63) >> 1;
                int ii = (i < 16) ? i : i - 16;
                float freq = (1.0f + (float)ii * (4.0f / 15.0f)) * PI_F;
                int fsel = (i >= 16) ? 1 : 0;
                #pragma unroll
                for (int r = 0; r < 4; ++r) {
                    int row = bm + mi * 32 + wr * 16 + lg * 4 + r;
                    float val = acc[mi][nj][r];
                    float par = __shfl_xor(val, 1);
                    int nn = row & 1023;
                    float ang = fbq[nn * 2 + fsel] * freq;
                    float sv, cv;
                    __sincosf(ang, &sv, &cv);
                    float ca = cv * age, sg = sv * gen;
                    float res = (col & 1) ? (val * ca + par * sg)
                                          : (val * ca - par * sg);
                    if (col < 1024)
                        Cout[(size_t)row * 1024 + col] = f2bf(res * 0.125f);
                    else
                        Cout2[(size_t)row * 1024 + col - 1024] = f2bf(res);
                }
            }
        }
        return;
    }

    #pragma unroll
    for (int mi = 0; mi < 8; ++mi) {
        int row = bm + mi * 32 + wr * 16 + lg * 4;
        #pragma unroll
        for (int nj = 0; nj < 4; ++nj) {
            int col = bn + nj * 64 + wc * 16 + lk;
            #pragma unroll
            for (int r = 0; r < 4; ++r) {
                float v = acc[mi][nj][r] + bias[col];
                if (EPI == 2) {
                    float u = v * 0.7978845608f * (1.0f + 0.044715f * v * v);
                    v = v / (1.0f + __expf(-2.0f * u));
                }
                Cout[(size_t)(row + r) * ldc + col] = f2bf(v);
            }
        }
    }
}

// ---------------------------------------------------------------------------
// 8-phase counted-vmcnt GEMM, BM=128 x BN=256 (r22 new ledger): grid stays
// 256 blocks (all CUs) for N=1024 outputs. A-half = 64 rows = 8KB = 1 gload/
// thread; B-half = 128 rows = 16KB = 2 gloads/thread. Simulated in-flight
// ledger: prologue 11 loads -> vmcnt(8); loop gates ph0->vmcnt(7),
// ph1->vmcnt(7), ph2->BAR only, ph3->vmcnt(8). Tail clamped (never read).
// LDS 2 x (A 16KB ++ B 32KB) = 96KB -> 1 blk/CU. EPI: 0=none 1=+bias.
// ---------------------------------------------------------------------------
template<int EPI>
__global__ __launch_bounds__(512, 2) void gemm8pB(
    const unsigned short* __restrict__ A,
    const unsigned short* __restrict__ Bt,
    const float* __restrict__ bias,
    unsigned short* __restrict__ Cout,
    int M, int Nn, int K, int ldc)
{
    __shared__ unsigned char lds[98304];        // 2 bufs x (A 16KB ++ B 32KB)
    const int tid = threadIdx.x;
    const int w = tid >> 6, lane = tid & 63;
    const int lk = lane & 15, lg = lane >> 4;
    const int wr = w >> 2, wc = w & 3;
    const int nbn = Nn >> 8;
    const int nb = gridDim.x;
    int bid = blockIdx.x;
    int swz = (nb & 7) ? bid : (bid & 7) * (nb >> 3) + (bid >> 3);
    const int bm = (swz / nbn) << 7, bn = (swz % nbn) << 8;

    f32x4 acc[4][4] = {};
    bf16x8 af[2][2];
    bf16x8 bfr[2][2][2];

    // op 0=A (half = 64 rows, 1 load/thread), 1=B (half = 128 rows, 2 loads)
    auto stageA = [&](int buf, int half, int kt) {
        int s = tid;                            // 512 slots of 16B
        int r = s >> 3, c = s & 7;
        int cs = c ^ (r & 7);
        GLL16(A + (size_t)(bm + half * 64 + r) * K + kt + cs * 8,
              &lds[buf * 49152 + half * 8192 + s * 16]);
    };
    auto stageB = [&](int buf, int half, int kt) {
        #pragma unroll
        for (int i = 0; i < 2; ++i) {
            int s = tid + i * 512;              // 1024 slots of 16B
            int r = s >> 3, c = s & 7;
            int cs = c ^ (r & 7);
            GLL16(Bt + (size_t)(bn + half * 128 + r) * K + kt + cs * 8,
                  &lds[buf * 49152 + 16384 + half * 16384 + s * 16]);
        }
    };
    auto rdA = [&](int buf, int ah) {
        #pragma unroll
        for (int ml = 0; ml < 2; ++ml) {
            int row = (ah * 2 + ml) * 32 + wr * 16 + lk;   // [ah*64, ah*64+64)
            #pragma unroll
            for (int kk = 0; kk < 2; ++kk) {
                int sl = (kk * 4 + lg) ^ (row & 7);
                af[ml][kk] = *(const bf16x8*)&lds[buf * 49152 + row * 128 + sl * 16];
            }
        }
    };
    auto rdB = [&](int buf, int g) {
        #pragma unroll
        for (int njl = 0; njl < 2; ++njl) {
            int row = (g * 2 + njl) * 64 + wc * 16 + lk;
            #pragma unroll
            for (int kk = 0; kk < 2; ++kk) {
                int sl = (kk * 4 + lg) ^ (row & 7);
                bfr[g][njl][kk] = *(const bf16x8*)&lds[buf * 49152 + 16384 + row * 128 + sl * 16];
            }
        }
    };
    auto mfmaq = [&](int ah, int g) {
        __builtin_amdgcn_s_setprio(1);
        #pragma unroll
        for (int ml = 0; ml < 2; ++ml)
            #pragma unroll
            for (int njl = 0; njl < 2; ++njl)
                #pragma unroll
                for (int kk = 0; kk < 2; ++kk)
                    acc[ah * 2 + ml][g * 2 + njl] =
                        __builtin_amdgcn_mfma_f32_16x16x32_bf16(
                            af[ml][kk], bfr[g][njl][kk],
                            acc[ah * 2 + ml][g * 2 + njl], 0, 0, 0);
        __builtin_amdgcn_s_setprio(0);
    };

    const int NT = K >> 6;
    // prologue: A0_0(1) B0_0(2) B1_0(2) A1_0(1) A0_1(1) B0_1(2) B1_1(2) = 11
    stageA(0, 0, 0);
    stageB(0, 0, 0);
    stageB(0, 1, 0);
    stageA(0, 1, 0);
    stageA(1, 0, 64);
    stageB(1, 0, 64);
    stageB(1, 1, 64);
    VMW(8); BAR();                 // A0_0,B0_0 (3 oldest) landed

    for (int t = 0; t < NT; ++t) {
        const int buf = t & 1;
        const int t1 = (t + 1 < NT) ? t + 1 : NT - 1;   // clamped (never read)
        const int t2 = (t + 2 < NT) ? t + 2 : NT - 1;
        const int k1 = t1 << 6, k2 = t2 << 6;
        // ph0: reads A0,B0(t); stages A1(t+1)
        rdA(buf, 0); rdB(buf, 0);
        stageA(buf ^ 1, 1, k1);
        mfmaq(0, 0);
        VMW(7); BAR();             // B1_t (2) retired
        // ph1: reads B1(t); stages A0(t+2)
        rdB(buf, 1);
        stageA(buf, 0, k2);
        mfmaq(0, 1);
        VMW(7); BAR();             // A1_t (1) retired
        // ph2: reads A1(t); stages B0(t+2); successor reads nothing
        rdA(buf, 1);
        stageB(buf, 0, k2);
        mfmaq(1, 0);
        BAR();
        // ph3: regs only; stages B1(t+2)
        stageB(buf, 1, k2);
        mfmaq(1, 1);
        VMW(8); BAR();             // A0,B0 of t+1 (3 oldest) retired
    }
    VMW(0);
    BAR();

    #pragma unroll
    for (int mi = 0; mi < 4; ++mi) {
        int row = bm + mi * 32 + wr * 16 + lg * 4;
        #pragma unroll
        for (int nj = 0; nj < 4; ++nj) {
            int col = bn + nj * 64 + wc * 16 + lk;
            #pragma unroll
            for (int r = 0; r < 4; ++r) {
                float v = acc[mi][nj][r];
                if (EPI >= 1) v += bias[col];
                Cout[(size_t)(row + r) * ldc + col] = f2bf(v);
            }
        }
    }
}

// ---------------------------------------------------------------------------
__global__ __launch_bounds__(256) void cvt_bf16(
    const float* __restrict__ src, unsigned short* __restrict__ dst, int n)
{
    int i = (blockIdx.x * 256 + threadIdx.x) * 4;
    if (i < n) {
        float4 v = *(const float4*)(src + i);
        u16x4 o = { f2bf(v.x), f2bf(v.y), f2bf(v.z), f2bf(v.w) };
        *(u16x4*)(dst + i) = o;
    }
}

// ---------------------------------------------------------------------------
__global__ __launch_bounds__(256) void transpose_cvt(
    const float* __restrict__ src, unsigned short* __restrict__ dst, int R, int Cc)
{
    __shared__ float t[32][33];
    const int bc = blockIdx.x * 32, br = blockIdx.y * 32;
    const int tx = threadIdx.x & 31, ty = threadIdx.x >> 5;
    #pragma unroll
    for (int i = 0; i < 4; ++i)
        t[ty + i * 8][tx] = src[(size_t)(br + ty + i * 8) * Cc + bc + tx];
    __syncthreads();
    #pragma unroll
    for (int i = 0; i < 4; ++i)
        dst[(size_t)(bc + ty + i * 8) * R + br + tx] = f2bf(t[tx][ty + i * 8]);
}

// ---------------------------------------------------------------------------
// Flash attention, swapped-operand + defer-max/setprio + QBLK=128 (r17-best).
// ---------------------------------------------------------------------------
__global__ __launch_bounds__(256, 4) void attn_mfma(
    const unsigned short* __restrict__ Q, const unsigned short* __restrict__ K,
    const unsigned short* __restrict__ V, unsigned short* __restrict__ O,
    int B, int H, int N)
{
    __shared__ unsigned short Ks[64 * 64];
    __shared__ unsigned short Vt[64 * 72];
    __shared__ unsigned short Ps[4][16 * 72];

    const int bi = blockIdx.x;
    const int bh = (bi & 7) + 8 * ((bi >> 3) & 15);
    const int q0 = (bi >> 7) * 128;
    const int b = bh >> 4, h = bh & 15;
    const int tid = threadIdx.x;
    const int w = tid >> 6, lane = tid & 63;
    const int lg = lane >> 4, lk = lane & 15;

    bf16x8 qf[2][2];
    #pragma unroll
    for (int qt = 0; qt < 2; ++qt) {
        const unsigned short* qrow =
            Q + (size_t)(b * N + q0 + qt * 64 + w * 16 + lk) * 1024 + h * 64;
        qf[qt][0] = *(const bf16x8*)(qrow + lg * 8);
        qf[qt][1] = *(const bf16x8*)(qrow + 32 + lg * 8);
    }

    f32x4 o[2][4] = {};
    float m_run[2] = { -INFINITY, -INFINITY }, l_run[2] = { 0.f, 0.f };

    for (int t0 = 0; t0 < N; t0 += 64) {
        const size_t kvbase = (size_t)(b * N + t0) * 1024 + h * 64;
        #pragma unroll
        for (int it = 0; it < 2; ++it) {
            int s = it * 256 + tid;
            int row = s >> 3, cb = (s & 7) << 4;
            int dby = cb ^ ((row & 7) << 4);
            GLL16(K + kvbase + (size_t)row * 1024 + (dby >> 1), &Ks[s * 8]);
        }
        {
            int c = tid >> 5, k0 = (tid & 31) * 2;
            const unsigned short* vp = V + kvbase + (size_t)k0 * 1024 + c * 8;
            u16x8 va = *(const u16x8*)vp;
            u16x8 vb = *(const u16x8*)(vp + 1024);
            #pragma unroll
            for (int j = 0; j < 8; ++j) {
                unsigned val = (unsigned)va[j] | ((unsigned)vb[j] << 16);
                *(unsigned*)&Vt[(c * 8 + j) * 72 + k0] = val;
            }
        }
        __syncthreads();

        #pragma unroll
        for (int qt = 0; qt < 2; ++qt) {
            f32x4 s4[4];
            __builtin_amdgcn_s_setprio(1);
            #pragma unroll
            for (int sub = 0; sub < 4; ++sub) {
                f32x4 acc = {0.f, 0.f, 0.f, 0.f};
                #pragma unroll
                for (int kh = 0; kh < 2; ++kh) {
                    int cc = (kh * 64 + lg * 16) ^ ((lk & 7) << 4);
                    bf16x8 kf = *(const bf16x8*)&Ks[(sub * 16 + lk) * 64 + (cc >> 1)];
                    acc = __builtin_amdgcn_mfma_f32_16x16x32_bf16(kf, qf[qt][kh], acc, 0, 0, 0);
                }
                s4[sub] = acc;
            }
            __builtin_amdgcn_s_setprio(0);

            float pmax = -INFINITY;
            #pragma unroll
            for (int sub = 0; sub < 4; ++sub)
                #pragma unroll
                for (int r = 0; r < 4; ++r) pmax = fmaxf(pmax, s4[sub][r]);
            pmax = fmaxf(pmax, __shfl_xor(pmax, 16));
            pmax = fmaxf(pmax, __shfl_xor(pmax, 32));

            if (!__all(pmax - m_run[qt] <= 8.0f)) {
                float mn = fmaxf(m_run[qt], pmax);
                float corr = __expf(m_run[qt] - mn);
                m_run[qt] = mn;
                l_run[qt] *= corr;
                #pragma unroll
                for (int ds = 0; ds < 4; ++ds)
                    #pragma unroll
                    for (int r = 0; r < 4; ++r) o[qt][ds][r] *= corr;
            }

            float psum = 0.f;
            unsigned pw[4][2];
            #pragma unroll
            for (int sub = 0; sub < 4; ++sub) {
                float p0 = __expf(s4[sub][0] - m_run[qt]);
                float p1 = __expf(s4[sub][1] - m_run[qt]);
                float p2 = __expf(s4[sub][2] - m_run[qt]);
                float p3 = __expf(s4[sub][3] - m_run[qt]);
                psum += (p0 + p1) + (p2 + p3);
                pw[sub][0] = (__float_as_uint(p0) >> 16) | (__float_as_uint(p1) & 0xffff0000u);
                pw[sub][1] = (__float_as_uint(p2) >> 16) | (__float_as_uint(p3) & 0xffff0000u);
            }
            psum += __shfl_xor(psum, 16);
            psum += __shfl_xor(psum, 32);
            l_run[qt] += psum;
            #pragma unroll
            for (int sub = 0; sub < 4; ++sub) {
                *(unsigned*)&Ps[w][lk * 72 + sub * 16 + lg * 4]     = pw[sub][0];
                *(unsigned*)&Ps[w][lk * 72 + sub * 16 + lg * 4 + 2] = pw[sub][1];
            }
            asm volatile("s_waitcnt lgkmcnt(0)" ::: "memory");

            __builtin_amdgcn_s_setprio(1);
            #pragma unroll
            for (int kh = 0; kh < 2; ++kh) {
                bf16x8 pf = *(const bf16x8*)&Ps[w][lk * 72 + kh * 32 + lg * 8];
                #pragma unroll
                for (int ds = 0; ds < 4; ++ds) {
                    bf16x8 vf = *(const bf16x8*)&Vt[(ds * 16 + lk) * 72 + kh * 32 + lg * 8];
                    o[qt][ds] = __builtin_amdgcn_mfma_f32_16x16x32_bf16(vf, pf, o[qt][ds], 0, 0, 0);
                }
            }
            __builtin_amdgcn_s_setprio(0);
        }
        __syncthreads();
    }

    #pragma unroll
    for (int qt = 0; qt < 2; ++qt) {
        unsigned short* orow =
            O + (size_t)(b * N + q0 + qt * 64 + w * 16 + lk) * 1024 + h * 64;
        float rinv = 1.0f / l_run[qt];
        #pragma unroll
        for (int ds = 0; ds < 4; ++ds) {
            u16x4 pk = { f2bf(o[qt][ds][0] * rinv), f2bf(o[qt][ds][1] * rinv),
                         f2bf(o[qt][ds][2] * rinv), f2bf(o[qt][ds][3] * rinv) };
            *(u16x4*)(orow + ds * 16 + lg * 4) = pk;
        }
    }
}

// ---------------------------------------------------------------------------
// Fused residual + LayerNorm: v = x + gamma*y; out f32 and/or bf16 (nullable).
// ---------------------------------------------------------------------------
template<int XBF>
__global__ __launch_bounds__(256) void ln_res3(
    const void* __restrict__ xv, const unsigned short* __restrict__ y1,
    const float* __restrict__ gamma, const float* __restrict__ w,
    const float* __restrict__ bia, float* __restrict__ out,
    unsigned short* __restrict__ out_bf, int C)
{
    const int row = blockIdx.x;
    __shared__ float buf[1024];
    __shared__ float red[8];
    const size_t base = (size_t)row * C;
    float s = 0.f, ss = 0.f;
    for (int c = threadIdx.x; c < C; c += 256) {
        float xf = XBF ? bf2f(((const unsigned short*)xv)[base + c])
                       : ((const float*)xv)[base + c];
        float v = xf + gamma[c] * bf2f(y1[base + c]);
        buf[c] = v; s += v; ss += v * v;
    }
    #pragma unroll
    for (int msk = 1; msk < 64; msk <<= 1) { s += __shfl_xor(s, msk); ss += __shfl_xor(ss, msk); }
    int wv = threadIdx.x >> 6, lane = threadIdx.x & 63;
    if (lane == 0) { red[wv * 2] = s; red[wv * 2 + 1] = ss; }
    __syncthreads();
    if (threadIdx.x == 0) {
        float S = 0.f, SS = 0.f;
        #pragma unroll
        for (int i = 0; i < 4; ++i) { S += red[2 * i]; SS += red[2 * i + 1]; }
        red[0] = S; red[1] = SS;
    }
    __syncthreads();
    float mu = red[0] / C;
    float var = red[1] / C - mu * mu;
    float rstd = rsqrtf(var + 1e-5f);
    for (int c = threadIdx.x; c < C; c += 256) {
        float v = (buf[c] - mu) * rstd * w[c] + bia[c];
        if (out) out[base + c] = v;
        if (out_bf) out_bf[base + c] = f2bf(v);
    }
}

// ---------------------------------------------------------------------------
extern "C" void kernel_launch(void* const* d_in, const int* in_sizes, int n_in,
                              void* d_out, int out_size, void* d_ws, size_t ws_size,
                              hipStream_t stream)
{
    const float* x      = (const float*)d_in[0];
    const float* demo   = (const float*)d_in[1];
    const float* expl   = (const float*)d_in[2];
    const float* fb     = (const float*)d_in[3];
    const float* w_qkv  = (const float*)d_in[4];
    const float* w_proj = (const float*)d_in[5];
    const float* b_proj = (const float*)d_in[6];
    const float* gamma1 = (const float*)d_in[7];
    const float* gamma2 = (const float*)d_in[8];
    const float* ln1_w  = (const float*)d_in[9];
    const float* ln1_b  = (const float*)d_in[10];
    const float* ln2_w  = (const float*)d_in[11];
    const float* ln2_b  = (const float*)d_in[12];
    const float* w1     = (const float*)d_in[13];
    const float* b1     = (const float*)d_in[14];
    const float* w2     = (const float*)d_in[15];
    const float* b2     = (const float*)d_in[16];
    float* out = (float*)d_out;

    const int B = 8, N = 1024, C = 1024, F = 4096, H = 16;
    const int M = B * N;                        // 8192
    const size_t Mi = 1048576;

    float* ws = (float*)d_ws;
    unsigned short* Obf  = (unsigned short*)ws;              // M x 1024 bf16
    unsigned short* H2   = (unsigned short*)ws;
    unsigned short* Qbf  = (unsigned short*)(ws + 8 * Mi);
    unsigned short* Kbf  = (unsigned short*)(ws + 12 * Mi);
    unsigned short* Vbf  = (unsigned short*)(ws + 16 * Mi);
    unsigned short* Hid  = (unsigned short*)(ws + 8 * Mi);   // M x 4096 bf16
    unsigned short* Ebf  = (unsigned short*)(ws + 24 * Mi);
    unsigned short* Xbf  = (unsigned short*)(ws + 28 * Mi);
    unsigned short* Pb   = (unsigned short*)(ws + 24 * Mi);
    unsigned short* X1bf = (unsigned short*)(ws + 40 * Mi);
    unsigned short* Wt   = (unsigned short*)(ws + 44 * Mi);
    unsigned short* wqkvT  = Wt;                             // [3072][1024]
    unsigned short* wprojT = Wt + (size_t)3145728;           // [1024][1024]
    unsigned short* w1T    = wprojT + (size_t)1048576;       // [4096][1024]
    unsigned short* w2T    = w1T + (size_t)4194304;          // [1024][4096]

    dim3 blk(256);
    dim3 blk5(512);
    const int MC = M * C;

    hipLaunchKernelGGL(cvt_bf16, dim3(MC / 1024), blk, 0, stream, expl, Ebf, MC);
    hipLaunchKernelGGL(cvt_bf16, dim3(MC / 1024), blk, 0, stream, x, Xbf, MC);
    hipLaunchKernelGGL(transpose_cvt, dim3(96, 32), blk, 0, stream, w_qkv, wqkvT, C, 3 * C);
    hipLaunchKernelGGL(transpose_cvt, dim3(32, 32), blk, 0, stream, w_proj, wprojT, C, C);
    hipLaunchKernelGGL(transpose_cvt, dim3(128, 32), blk, 0, stream, w1, w1T, C, F);
    hipLaunchKernelGGL(transpose_cvt, dim3(32, 128), blk, 0, stream, w2, w2T, F, C);

    // QK projection with FUSED drofe [8p BM256] -> Qbf (scaled) + Kbf
    hipLaunchKernelGGL((gemm8p<3>), dim3(32 * 8), blk5, 0, stream, Ebf, wqkvT,
                       (const float*)nullptr, Qbf, Kbf, fb, demo, M, 2048, C, 2048);
    // V projection [8p BM128, 256 blocks]
    hipLaunchKernelGGL((gemm8pB<0>), dim3(64 * 4), blk5, 0, stream, Xbf,
                       wqkvT + (size_t)2048 * 1024, (const float*)nullptr, Vbf,
                       M, 1024, C, 1024);

    // attention (QBLK=128) -> bf16 O
    hipLaunchKernelGGL(attn_mfma, dim3(B * H * (N / 128)), blk, 0, stream, Qbf, Kbf, Vbf, Obf, B, H, N);

    // output projection [8p BM128] -> bf16 Pb
    hipLaunchKernelGGL((gemm8pB<1>), dim3(64 * 4), blk5, 0, stream, Obf, wprojT, b_proj,
                       Pb, M, 1024, C, 1024);

    // residual + LN1: x f32 + gamma1*Pb -> X1bf only
    hipLaunchKernelGGL((ln_res3<0>), dim3(M), blk, 0, stream, (const void*)x, Pb,
                       gamma1, ln1_w, ln1_b, (float*)nullptr, X1bf, C);

    // MLP1 (gelu) [8p BM256] -> Hid
    hipLaunchKernelGGL((gemm8p<2>), dim3(32 * 16), blk5, 0, stream, X1bf, w1T, b1,
                       Hid, (unsigned short*)nullptr, (const float*)nullptr, (const float*)nullptr,
                       M, F, C, F);
    // MLP2 [8p BM128, K=4096] -> H2 bf16
    hipLaunchKernelGGL((gemm8pB<1>), dim3(64 * 4), blk5, 0, stream, Hid, w2T, b2,
                       H2, M, 1024, F, 1024);

    // residual + LN2: X1bf + gamma2*H2 -> out f32
    hipLaunchKernelGGL((ln_res3<1>), dim3(M), blk, 0, stream, (const void*)X1bf, H2,
                       gamma2, ln2_w, ln2_b, out, (unsigned short*)nullptr, C);
}

// Round 23
// 381.719 us; speedup vs baseline: 1.0173x; 1.0173x over previous
//
#include <hip/hip_runtime.h>
#include <hip/hip_bf16.h>
#include <math.h>

typedef __attribute__((ext_vector_type(8))) short bf16x8;
typedef __attribute__((ext_vector_type(8))) unsigned short u16x8;
typedef __attribute__((ext_vector_type(4))) float f32x4;
typedef __attribute__((ext_vector_type(4))) unsigned short u16x4;

__device__ inline unsigned short f2bf(float f) {
    union { float f; unsigned u; } v; v.f = f;
    unsigned r = (v.u + 0x7fff + ((v.u >> 16) & 1)) >> 16;   // RNE
    return (unsigned short)r;
}
__device__ inline float bf2f(unsigned short u) {
    union { unsigned u; float f; } v; v.u = ((unsigned)u) << 16; return v.f;
}

#define GLL16(gp, lp) __builtin_amdgcn_global_load_lds(                      \
    (const __attribute__((address_space(1))) void*)(gp),                     \
    (__attribute__((address_space(3))) void*)(lp), 16, 0, 0)

#define BAR() do { asm volatile("" ::: "memory");                            \
    __builtin_amdgcn_s_barrier();                                            \
    asm volatile("" ::: "memory"); } while (0)
#define VMW(n) asm volatile("s_waitcnt vmcnt(" #n ")" ::: "memory")

// ---------------------------------------------------------------------------
// 8-phase counted-vmcnt GEMM, BM=256 (r20/r21-verified: ~716 TF end-to-end;
// rocprof inflates this kernel's per-dispatch time). 256x256, BK=64, 8 waves,
// 128KB dbuf LDS. EPI=2: +bias+gelu. EPI=3: fused drofe (Q scaled -> Cout,
// K -> Cout2; rotation partner = lane^1).
// ---------------------------------------------------------------------------
template<int EPI>
__global__ __launch_bounds__(512, 2) void gemm8p(
    const unsigned short* __restrict__ A,
    const unsigned short* __restrict__ Bt,
    const float* __restrict__ bias,
    unsigned short* __restrict__ Cout,
    unsigned short* __restrict__ Cout2,
    const float* __restrict__ fbq,
    const float* __restrict__ demo,
    int M, int Nn, int K, int ldc)
{
    __shared__ unsigned char lds[131072];
    const int tid = threadIdx.x;
    const int w = tid >> 6, lane = tid & 63;
    const int lk = lane & 15, lg = lane >> 4;
    const int wr = w >> 2, wc = w & 3;
    const int nbn = Nn >> 8;
    const int nb = gridDim.x;
    int bid = blockIdx.x;
    int swz = (nb & 7) ? bid : (bid & 7) * (nb >> 3) + (bid >> 3);
    const int bm = (swz / nbn) << 8, bn = (swz % nbn) << 8;

    f32x4 acc[8][4] = {};
    bf16x8 af[4][2];
    bf16x8 bfr[2][2][2];

    auto stageH = [&](int buf, int op, int half, int kt) {
        #pragma unroll
        for (int i = 0; i < 2; ++i) {
            int s = tid + i * 512;
            int r = s >> 3, c = s & 7;
            int cs = c ^ (r & 7);
            const unsigned short* gp = (op == 0)
                ? A  + (size_t)(bm + half * 128 + r) * K + kt + cs * 8
                : Bt + (size_t)(bn + half * 128 + r) * K + kt + cs * 8;
            GLL16(gp, &lds[buf * 65536 + op * 32768 + half * 16384 + s * 16]);
        }
    };
    auto rdA = [&](int buf, int ah) {
        #pragma unroll
        for (int ml = 0; ml < 4; ++ml) {
            int row = (ah * 4 + ml) * 32 + wr * 16 + lk;
            #pragma unroll
            for (int kk = 0; kk < 2; ++kk) {
                int sl = (kk * 4 + lg) ^ (row & 7);
                af[ml][kk] = *(const bf16x8*)&lds[buf * 65536 + row * 128 + sl * 16];
            }
        }
    };
    auto rdB = [&](int buf, int g) {
        #pragma unroll
        for (int njl = 0; njl < 2; ++njl) {
            int row = (g * 2 + njl) * 64 + wc * 16 + lk;
            #pragma unroll
            for (int kk = 0; kk < 2; ++kk) {
                int sl = (kk * 4 + lg) ^ (row & 7);
                bfr[g][njl][kk] = *(const bf16x8*)&lds[buf * 65536 + 32768 + row * 128 + sl * 16];
            }
        }
    };
    auto mfmaq = [&](int ah, int g) {
        __builtin_amdgcn_s_setprio(1);
        #pragma unroll
        for (int ml = 0; ml < 4; ++ml)
            #pragma unroll
            for (int njl = 0; njl < 2; ++njl)
                #pragma unroll
                for (int kk = 0; kk < 2; ++kk)
                    acc[ah * 4 + ml][g * 2 + njl] =
                        __builtin_amdgcn_mfma_f32_16x16x32_bf16(
                            af[ml][kk], bfr[g][njl][kk],
                            acc[ah * 4 + ml][g * 2 + njl], 0, 0, 0);
        __builtin_amdgcn_s_setprio(0);
    };

    const int NT = K >> 6;
    stageH(0, 0, 0, 0);
    stageH(0, 1, 0, 0);
    stageH(0, 1, 1, 0);
    stageH(0, 0, 1, 0);
    stageH(1, 0, 0, 64);
    stageH(1, 1, 0, 64);
    stageH(1, 1, 1, 64);
    VMW(10); BAR();

    for (int t = 0; t < NT; ++t) {
        const int buf = t & 1;
        const int t1 = (t + 1 < NT) ? t + 1 : NT - 1;
        const int t2 = (t + 2 < NT) ? t + 2 : NT - 1;
        const int k1 = t1 << 6, k2 = t2 << 6;
        rdA(buf, 0); rdB(buf, 0);
        stageH(buf ^ 1, 0, 1, k1);
        mfmaq(0, 0);
        VMW(10); BAR();
        rdB(buf, 1);
        stageH(buf, 0, 0, k2);
        mfmaq(0, 1);
        VMW(10); BAR();
        rdA(buf, 1);
        stageH(buf, 1, 0, k2);
        mfmaq(1, 0);
        BAR();
        stageH(buf, 1, 1, k2);
        mfmaq(1, 1);
        VMW(10); BAR();
    }
    VMW(0);
    BAR();

    if (EPI == 3) {
        const float PI_F = 3.14159265358979323846f;
        const int b_ = bm >> 10;
        const float age = demo[b_ * 2 + 0], gen = demo[b_ * 2 + 1];
        #pragma unroll
        for (int mi = 0; mi < 8; ++mi) {
            #pragma unroll
            for (int nj = 0; nj < 4; ++nj) {
                int col = bn + nj * 64 + wc * 16 + lk;
                int i = (col & 63) >> 1;
                int ii = (i < 16) ? i : i - 16;
                float freq = (1.0f + (float)ii * (4.0f / 15.0f)) * PI_F;
                int fsel = (i >= 16) ? 1 : 0;
                #pragma unroll
                for (int r = 0; r < 4; ++r) {
                    int row = bm + mi * 32 + wr * 16 + lg * 4 + r;
                    float val = acc[mi][nj][r];
                    float par = __shfl_xor(val, 1);
                    int nn = row & 1023;
                    float ang = fbq[nn * 2 + fsel] * freq;
                    float sv, cv;
                    __sincosf(ang, &sv, &cv);
                    float ca = cv * age, sg = sv * gen;
                    float res = (col & 1) ? (val * ca + par * sg)
                                          : (val * ca - par * sg);
                    if (col < 1024)
                        Cout[(size_t)row * 1024 + col] = f2bf(res * 0.125f);
                    else
                        Cout2[(size_t)row * 1024 + col - 1024] = f2bf(res);
                }
            }
        }
        return;
    }

    #pragma unroll
    for (int mi = 0; mi < 8; ++mi) {
        int row = bm + mi * 32 + wr * 16 + lg * 4;
        #pragma unroll
        for (int nj = 0; nj < 4; ++nj) {
            int col = bn + nj * 64 + wc * 16 + lk;
            #pragma unroll
            for (int r = 0; r < 4; ++r) {
                float v = acc[mi][nj][r] + bias[col];
                if (EPI == 2) {
                    float u = v * 0.7978845608f * (1.0f + 0.044715f * v * v);
                    v = v / (1.0f + __expf(-2.0f * u));
                }
                Cout[(size_t)(row + r) * ldc + col] = f2bf(v);
            }
        }
    }
}

// ---------------------------------------------------------------------------
// bf16 MFMA GEMM (r15/r17-verified): 128x128, BK=32, 2ph dbuf, (256,4).
// EPI: 0=none 1=+bias 2=+bias+gelu.  (r22 A/B: 8pB BM128 was neutral vs this
// at K<=4096/N=1024 — occupancy overlap matches pipeline depth; keep 2ph.)
// ---------------------------------------------------------------------------
template<int EPI, int OUT_BF>
__global__ __launch_bounds__(256, 4) void gemm2ph128(
    const unsigned short* __restrict__ A,
    const unsigned short* __restrict__ Bt,
    const float* __restrict__ bias,
    void* __restrict__ Cout,
    int M, int Nn, int K, int ldc)
{
    __shared__ unsigned char lds[2][16384];
    const int tid = threadIdx.x;
    const int w = tid >> 6, lane = tid & 63;
    const int lk = lane & 15, lg = lane >> 4;
    const int wr = w >> 1, wc = w & 1;
    const int nbn = Nn >> 7;
    const int nb = gridDim.x;
    int bid = blockIdx.x;
    int swz = (nb & 7) ? bid : (bid & 7) * (nb >> 3) + (bid >> 3);
    const int bm = (swz / nbn) << 7, bn = (swz % nbn) << 7;

    f32x4 acc[4][4] = {};

    auto stage = [&](int buf, int k0) {
        #pragma unroll
        for (int i = 0; i < 4; ++i) {
            int s = tid + i * 256;
            int r = s >> 2, c = s & 3;
            int cs = (c ^ r ^ (r >> 2)) & 3;
            const unsigned short* gp = (r < 128)
                ? A  + (size_t)(bm + r) * K + k0 + cs * 8
                : Bt + (size_t)(bn + (r - 128)) * K + k0 + cs * 8;
            GLL16(gp, &lds[buf][s * 16]);
        }
    };

    const int NT = K >> 5;
    stage(0, 0);
    __syncthreads();
    int cur = 0;
    for (int t = 0; t < NT; ++t) {
        if (t + 1 < NT) stage(cur ^ 1, (t + 1) << 5);
        bf16x8 af[4], bfr[4];
        #pragma unroll
        for (int m = 0; m < 4; ++m) {
            int row = wr * 64 + m * 16 + lk;
            int sl = (lg ^ row ^ (row >> 2)) & 3;
            af[m] = *(const bf16x8*)&lds[cur][row * 64 + sl * 16];
        }
        #pragma unroll
        for (int n = 0; n < 4; ++n) {
            int row = wc * 64 + n * 16 + lk;
            int sl = (lg ^ row ^ (row >> 2)) & 3;
            bfr[n] = *(const bf16x8*)&lds[cur][8192 + row * 64 + sl * 16];
        }
        #pragma unroll
        for (int m = 0; m < 4; ++m)
            #pragma unroll
            for (int n = 0; n < 4; ++n)
                acc[m][n] = __builtin_amdgcn_mfma_f32_16x16x32_bf16(af[m], bfr[n], acc[m][n], 0, 0, 0);
        __syncthreads();
        cur ^= 1;
    }

    #pragma unroll
    for (int m = 0; m < 4; ++m) {
        int row = bm + wr * 64 + m * 16 + lg * 4;
        #pragma unroll
        for (int n = 0; n < 4; ++n) {
            int col = bn + wc * 64 + n * 16 + lk;
            #pragma unroll
            for (int r = 0; r < 4; ++r) {
                float v = acc[m][n][r];
                if (EPI >= 1) v += bias[col];
                if (EPI == 2) {
                    float u = v * 0.7978845608f * (1.0f + 0.044715f * v * v);
                    v = v / (1.0f + __expf(-2.0f * u));
                }
                if (OUT_BF)
                    ((unsigned short*)Cout)[(size_t)(row + r) * ldc + col] = f2bf(v);
                else
                    ((float*)Cout)[(size_t)(row + r) * ldc + col] = v;
            }
        }
    }
}

// ---------------------------------------------------------------------------
// dual fp32 -> bf16 convert (expl and x in one launch), 4 elems each/thread
// ---------------------------------------------------------------------------
__global__ __launch_bounds__(256) void cvt_bf16_dual(
    const float* __restrict__ s0, unsigned short* __restrict__ d0,
    const float* __restrict__ s1, unsigned short* __restrict__ d1, int n)
{
    int i = (blockIdx.x * 256 + threadIdx.x) * 4;
    if (i < n) {
        float4 a = *(const float4*)(s0 + i);
        u16x4 oa = { f2bf(a.x), f2bf(a.y), f2bf(a.z), f2bf(a.w) };
        *(u16x4*)(d0 + i) = oa;
        float4 b = *(const float4*)(s1 + i);
        u16x4 ob = { f2bf(b.x), f2bf(b.y), f2bf(b.z), f2bf(b.w) };
        *(u16x4*)(d1 + i) = ob;
    }
}

// ---------------------------------------------------------------------------
__global__ __launch_bounds__(256) void transpose_cvt(
    const float* __restrict__ src, unsigned short* __restrict__ dst, int R, int Cc)
{
    __shared__ float t[32][33];
    const int bc = blockIdx.x * 32, br = blockIdx.y * 32;
    const int tx = threadIdx.x & 31, ty = threadIdx.x >> 5;
    #pragma unroll
    for (int i = 0; i < 4; ++i)
        t[ty + i * 8][tx] = src[(size_t)(br + ty + i * 8) * Cc + bc + tx];
    __syncthreads();
    #pragma unroll
    for (int i = 0; i < 4; ++i)
        dst[(size_t)(bc + ty + i * 8) * R + br + tx] = f2bf(t[tx][ty + i * 8]);
}

// ---------------------------------------------------------------------------
// Flash attention, swapped-operand + defer-max/setprio + QBLK=128 (r17-best).
// ---------------------------------------------------------------------------
__global__ __launch_bounds__(256, 4) void attn_mfma(
    const unsigned short* __restrict__ Q, const unsigned short* __restrict__ K,
    const unsigned short* __restrict__ V, unsigned short* __restrict__ O,
    int B, int H, int N)
{
    __shared__ unsigned short Ks[64 * 64];
    __shared__ unsigned short Vt[64 * 72];
    __shared__ unsigned short Ps[4][16 * 72];

    const int bi = blockIdx.x;
    const int bh = (bi & 7) + 8 * ((bi >> 3) & 15);
    const int q0 = (bi >> 7) * 128;
    const int b = bh >> 4, h = bh & 15;
    const int tid = threadIdx.x;
    const int w = tid >> 6, lane = tid & 63;
    const int lg = lane >> 4, lk = lane & 15;

    bf16x8 qf[2][2];
    #pragma unroll
    for (int qt = 0; qt < 2; ++qt) {
        const unsigned short* qrow =
            Q + (size_t)(b * N + q0 + qt * 64 + w * 16 + lk) * 1024 + h * 64;
        qf[qt][0] = *(const bf16x8*)(qrow + lg * 8);
        qf[qt][1] = *(const bf16x8*)(qrow + 32 + lg * 8);
    }

    f32x4 o[2][4] = {};
    float m_run[2] = { -INFINITY, -INFINITY }, l_run[2] = { 0.f, 0.f };

    for (int t0 = 0; t0 < N; t0 += 64) {
        const size_t kvbase = (size_t)(b * N + t0) * 1024 + h * 64;
        #pragma unroll
        for (int it = 0; it < 2; ++it) {
            int s = it * 256 + tid;
            int row = s >> 3, cb = (s & 7) << 4;
            int dby = cb ^ ((row & 7) << 4);
            GLL16(K + kvbase + (size_t)row * 1024 + (dby >> 1), &Ks[s * 8]);
        }
        {
            int c = tid >> 5, k0 = (tid & 31) * 2;
            const unsigned short* vp = V + kvbase + (size_t)k0 * 1024 + c * 8;
            u16x8 va = *(const u16x8*)vp;
            u16x8 vb = *(const u16x8*)(vp + 1024);
            #pragma unroll
            for (int j = 0; j < 8; ++j) {
                unsigned val = (unsigned)va[j] | ((unsigned)vb[j] << 16);
                *(unsigned*)&Vt[(c * 8 + j) * 72 + k0] = val;
            }
        }
        __syncthreads();

        #pragma unroll
        for (int qt = 0; qt < 2; ++qt) {
            f32x4 s4[4];
            __builtin_amdgcn_s_setprio(1);
            #pragma unroll
            for (int sub = 0; sub < 4; ++sub) {
                f32x4 acc = {0.f, 0.f, 0.f, 0.f};
                #pragma unroll
                for (int kh = 0; kh < 2; ++kh) {
                    int cc = (kh * 64 + lg * 16) ^ ((lk & 7) << 4);
                    bf16x8 kf = *(const bf16x8*)&Ks[(sub * 16 + lk) * 64 + (cc >> 1)];
                    acc = __builtin_amdgcn_mfma_f32_16x16x32_bf16(kf, qf[qt][kh], acc, 0, 0, 0);
                }
                s4[sub] = acc;
            }
            __builtin_amdgcn_s_setprio(0);

            float pmax = -INFINITY;
            #pragma unroll
            for (int sub = 0; sub < 4; ++sub)
                #pragma unroll
                for (int r = 0; r < 4; ++r) pmax = fmaxf(pmax, s4[sub][r]);
            pmax = fmaxf(pmax, __shfl_xor(pmax, 16));
            pmax = fmaxf(pmax, __shfl_xor(pmax, 32));

            if (!__all(pmax - m_run[qt] <= 8.0f)) {
                float mn = fmaxf(m_run[qt], pmax);
                float corr = __expf(m_run[qt] - mn);
                m_run[qt] = mn;
                l_run[qt] *= corr;
                #pragma unroll
                for (int ds = 0; ds < 4; ++ds)
                    #pragma unroll
                    for (int r = 0; r < 4; ++r) o[qt][ds][r] *= corr;
            }

            float psum = 0.f;
            unsigned pw[4][2];
            #pragma unroll
            for (int sub = 0; sub < 4; ++sub) {
                float p0 = __expf(s4[sub][0] - m_run[qt]);
                float p1 = __expf(s4[sub][1] - m_run[qt]);
                float p2 = __expf(s4[sub][2] - m_run[qt]);
                float p3 = __expf(s4[sub][3] - m_run[qt]);
                psum += (p0 + p1) + (p2 + p3);
                pw[sub][0] = (__float_as_uint(p0) >> 16) | (__float_as_uint(p1) & 0xffff0000u);
                pw[sub][1] = (__float_as_uint(p2) >> 16) | (__float_as_uint(p3) & 0xffff0000u);
            }
            psum += __shfl_xor(psum, 16);
            psum += __shfl_xor(psum, 32);
            l_run[qt] += psum;
            #pragma unroll
            for (int sub = 0; sub < 4; ++sub) {
                *(unsigned*)&Ps[w][lk * 72 + sub * 16 + lg * 4]     = pw[sub][0];
                *(unsigned*)&Ps[w][lk * 72 + sub * 16 + lg * 4 + 2] = pw[sub][1];
            }
            asm volatile("s_waitcnt lgkmcnt(0)" ::: "memory");

            __builtin_amdgcn_s_setprio(1);
            #pragma unroll
            for (int kh = 0; kh < 2; ++kh) {
                bf16x8 pf = *(const bf16x8*)&Ps[w][lk * 72 + kh * 32 + lg * 8];
                #pragma unroll
                for (int ds = 0; ds < 4; ++ds) {
                    bf16x8 vf = *(const bf16x8*)&Vt[(ds * 16 + lk) * 72 + kh * 32 + lg * 8];
                    o[qt][ds] = __builtin_amdgcn_mfma_f32_16x16x32_bf16(vf, pf, o[qt][ds], 0, 0, 0);
                }
            }
            __builtin_amdgcn_s_setprio(0);
        }
        __syncthreads();
    }

    #pragma unroll
    for (int qt = 0; qt < 2; ++qt) {
        unsigned short* orow =
            O + (size_t)(b * N + q0 + qt * 64 + w * 16 + lk) * 1024 + h * 64;
        float rinv = 1.0f / l_run[qt];
        #pragma unroll
        for (int ds = 0; ds < 4; ++ds) {
            u16x4 pk = { f2bf(o[qt][ds][0] * rinv), f2bf(o[qt][ds][1] * rinv),
                         f2bf(o[qt][ds][2] * rinv), f2bf(o[qt][ds][3] * rinv) };
            *(u16x4*)(orow + ds * 16 + lg * 4) = pk;
        }
    }
}

// ---------------------------------------------------------------------------
// Fused residual + LayerNorm: v = x + gamma*y; out f32 and/or bf16 (nullable).
// ---------------------------------------------------------------------------
template<int XBF>
__global__ __launch_bounds__(256) void ln_res3(
    const void* __restrict__ xv, const unsigned short* __restrict__ y1,
    const float* __restrict__ gamma, const float* __restrict__ w,
    const float* __restrict__ bia, float* __restrict__ out,
    unsigned short* __restrict__ out_bf, int C)
{
    const int row = blockIdx.x;
    __shared__ float buf[1024];
    __shared__ float red[8];
    const size_t base = (size_t)row * C;
    float s = 0.f, ss = 0.f;
    for (int c = threadIdx.x; c < C; c += 256) {
        float xf = XBF ? bf2f(((const unsigned short*)xv)[base + c])
                       : ((const float*)xv)[base + c];
        float v = xf + gamma[c] * bf2f(y1[base + c]);
        buf[c] = v; s += v; ss += v * v;
    }
    #pragma unroll
    for (int msk = 1; msk < 64; msk <<= 1) { s += __shfl_xor(s, msk); ss += __shfl_xor(ss, msk); }
    int wv = threadIdx.x >> 6, lane = threadIdx.x & 63;
    if (lane == 0) { red[wv * 2] = s; red[wv * 2 + 1] = ss; }
    __syncthreads();
    if (threadIdx.x == 0) {
        float S = 0.f, SS = 0.f;
        #pragma unroll
        for (int i = 0; i < 4; ++i) { S += red[2 * i]; SS += red[2 * i + 1]; }
        red[0] = S; red[1] = SS;
    }
    __syncthreads();
    float mu = red[0] / C;
    float var = red[1] / C - mu * mu;
    float rstd = rsqrtf(var + 1e-5f);
    for (int c = threadIdx.x; c < C; c += 256) {
        float v = (buf[c] - mu) * rstd * w[c] + bia[c];
        if (out) out[base + c] = v;
        if (out_bf) out_bf[base + c] = f2bf(v);
    }
}

// ---------------------------------------------------------------------------
extern "C" void kernel_launch(void* const* d_in, const int* in_sizes, int n_in,
                              void* d_out, int out_size, void* d_ws, size_t ws_size,
                              hipStream_t stream)
{
    const float* x      = (const float*)d_in[0];
    const float* demo   = (const float*)d_in[1];
    const float* expl   = (const float*)d_in[2];
    const float* fb     = (const float*)d_in[3];
    const float* w_qkv  = (const float*)d_in[4];
    const float* w_proj = (const float*)d_in[5];
    const float* b_proj = (const float*)d_in[6];
    const float* gamma1 = (const float*)d_in[7];
    const float* gamma2 = (const float*)d_in[8];
    const float* ln1_w  = (const float*)d_in[9];
    const float* ln1_b  = (const float*)d_in[10];
    const float* ln2_w  = (const float*)d_in[11];
    const float* ln2_b  = (const float*)d_in[12];
    const float* w1     = (const float*)d_in[13];
    const float* b1     = (const float*)d_in[14];
    const float* w2     = (const float*)d_in[15];
    const float* b2     = (const float*)d_in[16];
    float* out = (float*)d_out;

    const int B = 8, N = 1024, C = 1024, F = 4096, H = 16;
    const int M = B * N;                        // 8192
    const size_t Mi = 1048576;

    float* ws = (float*)d_ws;
    unsigned short* Obf  = (unsigned short*)ws;              // M x 1024 bf16
    unsigned short* H2   = (unsigned short*)ws;
    unsigned short* Qbf  = (unsigned short*)(ws + 8 * Mi);
    unsigned short* Kbf  = (unsigned short*)(ws + 12 * Mi);
    unsigned short* Vbf  = (unsigned short*)(ws + 16 * Mi);
    unsigned short* Hid  = (unsigned short*)(ws + 8 * Mi);   // M x 4096 bf16
    unsigned short* Ebf  = (unsigned short*)(ws + 24 * Mi);
    unsigned short* Xbf  = (unsigned short*)(ws + 28 * Mi);
    unsigned short* Pb   = (unsigned short*)(ws + 24 * Mi);
    unsigned short* X1bf = (unsigned short*)(ws + 40 * Mi);
    unsigned short* Wt   = (unsigned short*)(ws + 44 * Mi);
    unsigned short* wqkvT  = Wt;                             // [3072][1024]
    unsigned short* wprojT = Wt + (size_t)3145728;           // [1024][1024]
    unsigned short* w1T    = wprojT + (size_t)1048576;       // [4096][1024]
    unsigned short* w2T    = w1T + (size_t)4194304;          // [1024][4096]

    dim3 blk(256);
    dim3 blk5(512);
    const int MC = M * C;

    hipLaunchKernelGGL(cvt_bf16_dual, dim3(MC / 1024), blk, 0, stream, expl, Ebf, x, Xbf, MC);
    hipLaunchKernelGGL(transpose_cvt, dim3(96, 32), blk, 0, stream, w_qkv, wqkvT, C, 3 * C);
    hipLaunchKernelGGL(transpose_cvt, dim3(32, 32), blk, 0, stream, w_proj, wprojT, C, C);
    hipLaunchKernelGGL(transpose_cvt, dim3(128, 32), blk, 0, stream, w1, w1T, C, F);
    hipLaunchKernelGGL(transpose_cvt, dim3(32, 128), blk, 0, stream, w2, w2T, F, C);

    // QK projection with FUSED drofe [8p BM256] -> Qbf (scaled) + Kbf
    hipLaunchKernelGGL((gemm8p<3>), dim3(32 * 8), blk5, 0, stream, Ebf, wqkvT,
                       (const float*)nullptr, Qbf, Kbf, fb, demo, M, 2048, C, 2048);
    // V projection [2ph128]
    hipLaunchKernelGGL((gemm2ph128<0,1>), dim3(64 * 8), blk, 0, stream, Xbf,
                       wqkvT + (size_t)2048 * 1024, (const float*)nullptr, (void*)Vbf,
                       M, 1024, C, 1024);

    // attention (QBLK=128) -> bf16 O
    hipLaunchKernelGGL(attn_mfma, dim3(B * H * (N / 128)), blk, 0, stream, Qbf, Kbf, Vbf, Obf, B, H, N);

    // output projection [2ph128] -> bf16 Pb
    hipLaunchKernelGGL((gemm2ph128<1,1>), dim3(64 * 8), blk, 0, stream, Obf, wprojT, b_proj,
                       (void*)Pb, M, 1024, C, 1024);

    // residual + LN1: x f32 + gamma1*Pb -> X1bf only
    hipLaunchKernelGGL((ln_res3<0>), dim3(M), blk, 0, stream, (const void*)x, Pb,
                       gamma1, ln1_w, ln1_b, (float*)nullptr, X1bf, C);

    // MLP1 (gelu) [8p BM256] -> Hid
    hipLaunchKernelGGL((gemm8p<2>), dim3(32 * 16), blk5, 0, stream, X1bf, w1T, b1,
                       Hid, (unsigned short*)nullptr, (const float*)nullptr, (const float*)nullptr,
                       M, F, C, F);
    // MLP2 [2ph128, K=4096] -> H2 bf16
    hipLaunchKernelGGL((gemm2ph128<1,1>), dim3(64 * 8), blk, 0, stream, Hid, w2T, b2,
                       (void*)H2, M, 1024, F, 1024);

    // residual + LN2: X1bf + gamma2*H2 -> out f32
    hipLaunchKernelGGL((ln_res3<1>), dim3(M), blk, 0, stream, (const void*)X1bf, H2,
                       gamma2, ln2_w, ln2_b, out, (unsigned short*)nullptr, C);
}